// Round 2
// baseline (262.068 us; speedup 1.0000x reference)
//
#include <hip/hip_runtime.h>
#include <math.h>

#define N_CH 128

// ---------------------------------------------------------------------------
// K0: V1t[k*128+o] = W[o][k] - W[o][128+k], V2t[k*128+o] = W[o][128+k];
//     zero per-node histogram + ticket.
// ---------------------------------------------------------------------------
__global__ __launch_bounds__(256) void prep_kernel(const float* __restrict__ W,
                                                   float* __restrict__ V1,
                                                   float* __restrict__ V2,
                                                   int* __restrict__ nodeCount,
                                                   int* __restrict__ done,
                                                   int n_nodes) {
    int i = blockIdx.x * 256 + threadIdx.x;
    if (i < N_CH * N_CH) {
        int k = i >> 7, o = i & 127;
        float w1 = W[o * 256 + k];
        float w2 = W[o * 256 + 128 + k];
        V1[i] = w1 - w2;
        V2[i] = w2;
    }
    int total = gridDim.x * 256;
    for (int j = i; j < n_nodes; j += total) nodeCount[j] = 0;
    if (i == 0) *done = 0;
}

// ---------------------------------------------------------------------------
// K1: fused GEMM + edge histogram + last-block scan.
//  - hist: each block atomicAdds its 1024-edge chunk into nodeCount[] (global,
//    L2-resident, overlapped with the FMA work below).
//  - gemm: A = x @ V1 + bias (fp32), Bh = bf16(x @ V2). 16 nodes/block.
//  - last finishing block (device-scope ticket) scans nodeCount -> offsets[],
//    cursor[]. Atomic reads (addend 0) so the values come from the coherent
//    point, not a possibly-stale local L2 line.
// ---------------------------------------------------------------------------
__global__ __launch_bounds__(256) void gemmhist_kernel(
        const float* __restrict__ x,
        const float* __restrict__ V1,
        const float* __restrict__ V2,
        const float* __restrict__ bias,
        const int* __restrict__ dst,
        float* __restrict__ A,
        unsigned short* __restrict__ Bh,
        int* __restrict__ nodeCount,
        int* __restrict__ done,
        int* __restrict__ offsets,
        int* __restrict__ cursor,
        int n_nodes, int n_edges, int ec) {
    __shared__ float xs[16][N_CH];      // 8 KB
    __shared__ int ps[256];
    __shared__ int isLast;
    const int tid = threadIdx.x;
    const int bid = blockIdx.x;

    // --- histogram chunk (issue first; atomics are fire-and-forget) ---
    {
        const int base = bid * ec;
        const int cnt = min(ec, n_edges - base);
        for (int j = tid; j < cnt; j += 256)
            atomicAdd(&nodeCount[dst[base + j]], 1);
    }

    // --- GEMM: 16 nodes per block ---
    const int n0 = bid * 16;
    if (n0 < n_nodes) {
        if (n0 + 16 <= n_nodes) {
            const float4* xg = (const float4*)(x + (size_t)n0 * N_CH);
            float4* xsv = (float4*)&xs[0][0];
            xsv[tid] = xg[tid];
            xsv[tid + 256] = xg[tid + 256];
        } else {
            for (int i = tid; i < 16 * N_CH; i += 256) {
                int n = n0 + (i >> 7);
                (&xs[0][0])[i] = (n < n_nodes) ? x[(size_t)n * N_CH + (i & 127)] : 0.f;
            }
        }
        __syncthreads();

        const int o  = tid & 127;
        const int nh = tid >> 7;            // 0 or 1 -> rows nh*8 .. nh*8+7
        const float bo = bias[o];
        float acc1[8], acc2[8];
        #pragma unroll
        for (int i = 0; i < 8; ++i) { acc1[i] = 0.f; acc2[i] = 0.f; }

        const float* xrow = &xs[nh * 8][0];
        for (int k4 = 0; k4 < N_CH; k4 += 4) {
            float w1[4], w2[4];
            #pragma unroll
            for (int j = 0; j < 4; ++j) {
                w1[j] = V1[(k4 + j) * N_CH + o];
                w2[j] = V2[(k4 + j) * N_CH + o];
            }
            #pragma unroll
            for (int i = 0; i < 8; ++i) {
                float4 xv = *(const float4*)&xrow[i * N_CH + k4];
                acc1[i] = fmaf(xv.x, w1[0], acc1[i]); acc2[i] = fmaf(xv.x, w2[0], acc2[i]);
                acc1[i] = fmaf(xv.y, w1[1], acc1[i]); acc2[i] = fmaf(xv.y, w2[1], acc2[i]);
                acc1[i] = fmaf(xv.z, w1[2], acc1[i]); acc2[i] = fmaf(xv.z, w2[2], acc2[i]);
                acc1[i] = fmaf(xv.w, w1[3], acc1[i]); acc2[i] = fmaf(xv.w, w2[3], acc2[i]);
            }
        }

        #pragma unroll
        for (int i = 0; i < 8; ++i) {
            int n = n0 + nh * 8 + i;
            if (n < n_nodes) {
                A[(size_t)n * N_CH + o] = acc1[i] + bo;
                unsigned int bits = __float_as_uint(acc2[i]);
                unsigned int r = (bits + 0x7FFFu + ((bits >> 16) & 1u)) >> 16;
                Bh[(size_t)n * N_CH + o] = (unsigned short)r;
            }
        }
    }

    // --- ticket: last block performs the node-offset scan ---
    __threadfence();
    __syncthreads();
    if (tid == 0) isLast = (atomicAdd(done, 1) == (int)gridDim.x - 1) ? 1 : 0;
    __syncthreads();
    if (!isLast) return;

    const int npt = (n_nodes + 255) >> 8;   // nodes per thread (40 for 10000)
    const int beg = tid * npt;
    int s = 0;
    for (int k = 0; k < npt; ++k) {
        int idx = beg + k;
        if (idx < n_nodes) s += atomicAdd(&nodeCount[idx], 0);
    }
    ps[tid] = s;
    __syncthreads();
    #pragma unroll
    for (int off = 1; off < 256; off <<= 1) {
        int u = (tid >= off) ? ps[tid - off] : 0;
        __syncthreads();
        ps[tid] += u;
        __syncthreads();
    }
    int run = ps[tid] - s;
    for (int k = 0; k < npt; ++k) {
        int idx = beg + k;
        if (idx < n_nodes) {
            int c = atomicAdd(&nodeCount[idx], 0);
            offsets[idx] = run;
            cursor[idx]  = run;
            run += c;
        }
    }
    if (tid == 255) offsets[n_nodes] = ps[255];
}

// ---------------------------------------------------------------------------
// K2: direct counting-sort scatter: eidx[atomicAdd(cursor[dst])] = src.
// 640K atomics spread over 10000 L2-resident counters; random 4B writes into
// the 2.56 MB eidx array (L2-absorbed).
// ---------------------------------------------------------------------------
__global__ __launch_bounds__(256) void scatter_kernel(const int* __restrict__ src,
                                                      const int* __restrict__ dst,
                                                      int* __restrict__ cursor,
                                                      int* __restrict__ eidx,
                                                      int n_edges) {
    const int g = blockIdx.x * 256 + threadIdx.x;
    const int base = g * 4;
    if (base + 4 <= n_edges) {
        int4 s4 = *(const int4*)(src + base);
        int4 d4 = *(const int4*)(dst + base);
        int p0 = atomicAdd(&cursor[d4.x], 1); eidx[p0] = s4.x;
        int p1 = atomicAdd(&cursor[d4.y], 1); eidx[p1] = s4.y;
        int p2 = atomicAdd(&cursor[d4.z], 1); eidx[p2] = s4.z;
        int p3 = atomicAdd(&cursor[d4.w], 1); eidx[p3] = s4.w;
    } else {
        for (int j = base; j < n_edges; ++j) {
            int p = atomicAdd(&cursor[dst[j]], 1);
            eidx[p] = src[j];
        }
    }
}

// ---------------------------------------------------------------------------
// K3: per-node gather-max. One WAVE per node, 4 nodes per block.
// 16 lanes cover one 256 B Bh row (uint4 = 8 channels/lane); the 4 sub-groups
// of the wave cover 4 edges per load instruction. Sub-groups merged at the
// end with a 2-step shfl_xor max-reduce.
// ---------------------------------------------------------------------------
__global__ __launch_bounds__(256) void gather_kernel(
        const float* __restrict__ A,
        const uint4* __restrict__ Bh4,   // n_nodes x 16 uint4 (128 bf16)
        const int* __restrict__ offsets,
        const int* __restrict__ eidx,
        float* __restrict__ out,
        int n_nodes) {
    __shared__ int sidx[4][64];
    const int g = threadIdx.x >> 6;
    const int l = threadIdx.x & 63;
    const int n = blockIdx.x * 4 + g;
    if (n >= n_nodes) return;
    const int beg = offsets[n], end = offsets[n + 1];

    const int sub = l >> 4;   // which of 4 edges within a load group
    const int col = l & 15;   // 16 B column within the 256 B row

    float mlo[4][4], mhi[4][4];
    #pragma unroll
    for (int s = 0; s < 4; ++s)
        #pragma unroll
        for (int u = 0; u < 4; ++u) { mlo[s][u] = -INFINITY; mhi[s][u] = -INFINITY; }

    for (int base = beg; base < end; base += 64) {
        int p = base + l;
        if (p < end) sidx[g][l] = eidx[p];
        // single-wave lockstep: same-wave DS ordering makes the write visible
        int cnt = min(64, end - base);
        int q = 0;
        for (; q + 16 <= cnt; q += 16) {
            int e[4];
            #pragma unroll
            for (int s = 0; s < 4; ++s) e[s] = sidx[g][q + 4 * s + sub];
            uint4 w[4];
            #pragma unroll
            for (int s = 0; s < 4; ++s) w[s] = Bh4[(size_t)e[s] * 16 + col];
            #pragma unroll
            for (int s = 0; s < 4; ++s) {
                mlo[s][0] = fmaxf(mlo[s][0], __uint_as_float(w[s].x << 16));
                mhi[s][0] = fmaxf(mhi[s][0], __uint_as_float(w[s].x & 0xFFFF0000u));
                mlo[s][1] = fmaxf(mlo[s][1], __uint_as_float(w[s].y << 16));
                mhi[s][1] = fmaxf(mhi[s][1], __uint_as_float(w[s].y & 0xFFFF0000u));
                mlo[s][2] = fmaxf(mlo[s][2], __uint_as_float(w[s].z << 16));
                mhi[s][2] = fmaxf(mhi[s][2], __uint_as_float(w[s].z & 0xFFFF0000u));
                mlo[s][3] = fmaxf(mlo[s][3], __uint_as_float(w[s].w << 16));
                mhi[s][3] = fmaxf(mhi[s][3], __uint_as_float(w[s].w & 0xFFFF0000u));
            }
        }
        for (; q < cnt; q += 4) {
            int r = q + sub;
            if (r < cnt) {
                int e = sidx[g][r];
                uint4 w = Bh4[(size_t)e * 16 + col];
                mlo[0][0] = fmaxf(mlo[0][0], __uint_as_float(w.x << 16));
                mhi[0][0] = fmaxf(mhi[0][0], __uint_as_float(w.x & 0xFFFF0000u));
                mlo[0][1] = fmaxf(mlo[0][1], __uint_as_float(w.y << 16));
                mhi[0][1] = fmaxf(mhi[0][1], __uint_as_float(w.y & 0xFFFF0000u));
                mlo[0][2] = fmaxf(mlo[0][2], __uint_as_float(w.z << 16));
                mhi[0][2] = fmaxf(mhi[0][2], __uint_as_float(w.z & 0xFFFF0000u));
                mlo[0][3] = fmaxf(mlo[0][3], __uint_as_float(w.w << 16));
                mhi[0][3] = fmaxf(mhi[0][3], __uint_as_float(w.w & 0xFFFF0000u));
            }
        }
    }

    // merge the 4 load slots
    float lo[4], hi[4];
    #pragma unroll
    for (int u = 0; u < 4; ++u) {
        lo[u] = fmaxf(fmaxf(mlo[0][u], mlo[1][u]), fmaxf(mlo[2][u], mlo[3][u]));
        hi[u] = fmaxf(fmaxf(mhi[0][u], mhi[1][u]), fmaxf(mhi[2][u], mhi[3][u]));
    }
    // reduce across the 4 sub-groups (lanes sharing `col`)
    #pragma unroll
    for (int u = 0; u < 4; ++u) {
        lo[u] = fmaxf(lo[u], __shfl_xor(lo[u], 16, 64));
        hi[u] = fmaxf(hi[u], __shfl_xor(hi[u], 16, 64));
        lo[u] = fmaxf(lo[u], __shfl_xor(lo[u], 32, 64));
        hi[u] = fmaxf(hi[u], __shfl_xor(hi[u], 32, 64));
    }

    if (sub == 0) {
        float r8[8];
        if (end > beg) {
            const float4* Arow = (const float4*)(A + (size_t)n * N_CH + col * 8);
            float4 a0 = Arow[0], a1 = Arow[1];
            r8[0] = a0.x + lo[0]; r8[1] = a0.y + hi[0];
            r8[2] = a0.z + lo[1]; r8[3] = a0.w + hi[1];
            r8[4] = a1.x + lo[2]; r8[5] = a1.y + hi[2];
            r8[6] = a1.z + lo[3]; r8[7] = a1.w + hi[3];
        } else {
            #pragma unroll
            for (int i = 0; i < 8; ++i) r8[i] = 0.f;
        }
        float4* orow = (float4*)(out + (size_t)n * N_CH + col * 8);
        orow[0] = make_float4(r8[0], r8[1], r8[2], r8[3]);
        orow[1] = make_float4(r8[4], r8[5], r8[6], r8[7]);
    }
}

// ---------------------------------------------------------------------------
extern "C" void kernel_launch(void* const* d_in, const int* in_sizes, int n_in,
                              void* d_out, int out_size, void* d_ws, size_t ws_size,
                              hipStream_t stream) {
    const float* x = (const float*)d_in[0];
    const float* W = (const float*)d_in[1];
    const float* b = (const float*)d_in[2];
    const int*   ei = (const int*)d_in[3];

    const int n_nodes = in_sizes[0] / N_CH;   // 10000
    const int n_edges = in_sizes[3] / 2;      // 640000
    const int* src = ei;
    const int* dst = ei + n_edges;
    float* out = (float*)d_out;

    char* ws = (char*)d_ws;
    size_t off = 0;
    auto alloc = [&](size_t bytes) -> void* {
        void* p = ws + off;
        off += (bytes + 255) & ~(size_t)255;
        return p;
    };
    float* V1        = (float*)alloc((size_t)N_CH * N_CH * 4);
    float* V2        = (float*)alloc((size_t)N_CH * N_CH * 4);
    float* A         = (float*)alloc((size_t)n_nodes * N_CH * 4);
    unsigned short* Bh = (unsigned short*)alloc((size_t)n_nodes * N_CH * 2);
    int*   nodeCount = (int*)alloc((size_t)n_nodes * 4);
    int*   done      = (int*)alloc(256);
    int*   offsets   = (int*)alloc((size_t)(n_nodes + 1) * 4);
    int*   cursor    = (int*)alloc((size_t)n_nodes * 4);
    int*   eidx      = (int*)alloc((size_t)n_edges * 4);
    (void)ws_size; (void)n_in; (void)out_size;

    const int ng = (n_nodes + 15) / 16;                 // 625 gemm+hist blocks
    const int ec = (n_edges + ng - 1) / ng;             // 1024 edges per block
    const int ns = (n_edges + 1023) / 1024;             // scatter blocks (4 edges/thread)

    prep_kernel   <<<64, 256, 0, stream>>>(W, V1, V2, nodeCount, done, n_nodes);
    gemmhist_kernel<<<ng, 256, 0, stream>>>(x, V1, V2, b, dst, A, Bh, nodeCount, done,
                                            offsets, cursor, n_nodes, n_edges, ec);
    scatter_kernel<<<ns, 256, 0, stream>>>(src, dst, cursor, eidx, n_edges);
    gather_kernel <<<(n_nodes + 3) / 4, 256, 0, stream>>>(A, (const uint4*)Bh, offsets, eidx, out, n_nodes);
}

// Round 3
// 200.375 us; speedup vs baseline: 1.3079x; 1.3079x over previous
//
#include <hip/hip_runtime.h>
#include <math.h>

#define N_CH 128
#define MAX_NPT 16   // scan: nodes per thread bound (n_nodes <= 16384)

// ---------------------------------------------------------------------------
// K0: V1t[k*128+o] = W[o][k] - W[o][128+k], V2t[k*128+o] = W[o][128+k];
//     zero per-node histogram.
// ---------------------------------------------------------------------------
__global__ __launch_bounds__(256) void prep_kernel(const float* __restrict__ W,
                                                   float* __restrict__ V1,
                                                   float* __restrict__ V2,
                                                   int* __restrict__ nodeCount,
                                                   int n_nodes) {
    int i = blockIdx.x * 256 + threadIdx.x;
    if (i < N_CH * N_CH) {
        int k = i >> 7, o = i & 127;
        float w1 = W[o * 256 + k];
        float w2 = W[o * 256 + 128 + k];
        V1[i] = w1 - w2;
        V2[i] = w2;
    }
    int total = gridDim.x * 256;
    for (int j = i; j < n_nodes; j += total) nodeCount[j] = 0;
}

// ---------------------------------------------------------------------------
// K1: A = x @ V1 + bias (fp32), Bh = bf16(x @ V2). fp32 VALU GEMM.
// (verified round-0 version: 32 nodes/block)
// ---------------------------------------------------------------------------
__global__ __launch_bounds__(256) void gemm_kernel(const float* __restrict__ x,
                                                   const float* __restrict__ V1,
                                                   const float* __restrict__ V2,
                                                   const float* __restrict__ bias,
                                                   float* __restrict__ A,
                                                   unsigned short* __restrict__ Bh,
                                                   int n_nodes) {
    __shared__ float xs[32][N_CH];      // 16 KB
    const int n0 = blockIdx.x * 32;
    const int tid = threadIdx.x;

    if (n0 + 32 <= n_nodes) {
        const float4* xg = (const float4*)(x + (size_t)n0 * N_CH);
        float4* xsv = (float4*)&xs[0][0];
        #pragma unroll
        for (int i = 0; i < 4; ++i) xsv[tid + i * 256] = xg[tid + i * 256];
    } else {
        for (int i = tid; i < 32 * N_CH; i += 256) {
            int n = n0 + (i >> 7);
            (&xs[0][0])[i] = (n < n_nodes) ? x[(size_t)n * N_CH + (i & 127)] : 0.f;
        }
    }
    __syncthreads();

    const int o  = tid & 127;
    const int nh = tid >> 7;            // 0 or 1
    const float bo = bias[o];
    float acc1[16], acc2[16];
    #pragma unroll
    for (int i = 0; i < 16; ++i) { acc1[i] = 0.f; acc2[i] = 0.f; }

    const float* xrow = &xs[nh * 16][0];
    for (int k4 = 0; k4 < N_CH; k4 += 4) {
        float w1[4], w2[4];
        #pragma unroll
        for (int j = 0; j < 4; ++j) {
            w1[j] = V1[(k4 + j) * N_CH + o];
            w2[j] = V2[(k4 + j) * N_CH + o];
        }
        #pragma unroll
        for (int i = 0; i < 16; ++i) {
            float4 xv = *(const float4*)&xrow[i * N_CH + k4];
            acc1[i] = fmaf(xv.x, w1[0], acc1[i]); acc2[i] = fmaf(xv.x, w2[0], acc2[i]);
            acc1[i] = fmaf(xv.y, w1[1], acc1[i]); acc2[i] = fmaf(xv.y, w2[1], acc2[i]);
            acc1[i] = fmaf(xv.z, w1[2], acc1[i]); acc2[i] = fmaf(xv.z, w2[2], acc2[i]);
            acc1[i] = fmaf(xv.w, w1[3], acc1[i]); acc2[i] = fmaf(xv.w, w2[3], acc2[i]);
        }
    }

    #pragma unroll
    for (int i = 0; i < 16; ++i) {
        int n = n0 + nh * 16 + i;
        if (n < n_nodes) {
            A[(size_t)n * N_CH + o] = acc1[i] + bo;
            // bf16 round-to-nearest-even
            unsigned int bits = __float_as_uint(acc2[i]);
            unsigned int r = (bits + 0x7FFFu + ((bits >> 16) & 1u)) >> 16;
            Bh[(size_t)n * N_CH + o] = (unsigned short)r;
        }
    }
}

// ---------------------------------------------------------------------------
// K2: per-node histogram. int4 dst loads, fire-and-forget global atomics
// (no return value -> global_atomic_add without sc0).
// ---------------------------------------------------------------------------
__global__ __launch_bounds__(256) void hist_kernel(const int* __restrict__ dst,
                                                   int* __restrict__ nodeCount,
                                                   int n_edges) {
    const int g = blockIdx.x * 256 + threadIdx.x;
    const int base = g * 4;
    if (base + 4 <= n_edges) {
        int4 d4 = *(const int4*)(dst + base);
        atomicAdd(&nodeCount[d4.x], 1);
        atomicAdd(&nodeCount[d4.y], 1);
        atomicAdd(&nodeCount[d4.z], 1);
        atomicAdd(&nodeCount[d4.w], 1);
    } else {
        for (int j = base; j < n_edges; ++j)
            atomicAdd(&nodeCount[dst[j]], 1);
    }
}

// ---------------------------------------------------------------------------
// K3: exclusive scan over n_nodes counts -> offsets[n_nodes+1], cursor.
// Single block, 1024 threads, PLAIN coalesced loads (kernel boundary made
// the histogram coherent), counts kept in registers between the two passes.
// ---------------------------------------------------------------------------
__global__ __launch_bounds__(1024) void scan_kernel(const int* __restrict__ nodeCount,
                                                    int* __restrict__ offsets,
                                                    int* __restrict__ cursor,
                                                    int n_nodes) {
    __shared__ int ps[1024];
    const int tid = threadIdx.x;
    const int npt = (n_nodes + 1023) >> 10;   // <= MAX_NPT
    const int beg = tid * npt;

    int c[MAX_NPT];
    int s = 0;
    for (int k = 0; k < npt; ++k) {
        int idx = beg + k;
        int v = (idx < n_nodes) ? nodeCount[idx] : 0;
        c[k] = v;
        s += v;
    }
    ps[tid] = s;
    __syncthreads();
    #pragma unroll
    for (int off = 1; off < 1024; off <<= 1) {
        int u = (tid >= off) ? ps[tid - off] : 0;
        __syncthreads();
        ps[tid] += u;
        __syncthreads();
    }
    int run = ps[tid] - s;
    for (int k = 0; k < npt; ++k) {
        int idx = beg + k;
        if (idx < n_nodes) {
            offsets[idx] = run;
            cursor[idx]  = run;
            run += c[k];
        }
    }
    if (tid == 1023) offsets[n_nodes] = ps[1023];
}

// ---------------------------------------------------------------------------
// K4: direct counting-sort scatter: eidx[atomicAdd(cursor[dst])] = src.
// ---------------------------------------------------------------------------
__global__ __launch_bounds__(256) void scatter_kernel(const int* __restrict__ src,
                                                      const int* __restrict__ dst,
                                                      int* __restrict__ cursor,
                                                      int* __restrict__ eidx,
                                                      int n_edges) {
    const int g = blockIdx.x * 256 + threadIdx.x;
    const int base = g * 4;
    if (base + 4 <= n_edges) {
        int4 s4 = *(const int4*)(src + base);
        int4 d4 = *(const int4*)(dst + base);
        int p0 = atomicAdd(&cursor[d4.x], 1); eidx[p0] = s4.x;
        int p1 = atomicAdd(&cursor[d4.y], 1); eidx[p1] = s4.y;
        int p2 = atomicAdd(&cursor[d4.z], 1); eidx[p2] = s4.z;
        int p3 = atomicAdd(&cursor[d4.w], 1); eidx[p3] = s4.w;
    } else {
        for (int j = base; j < n_edges; ++j) {
            int p = atomicAdd(&cursor[dst[j]], 1);
            eidx[p] = src[j];
        }
    }
}

// ---------------------------------------------------------------------------
// K5: per-node gather-max. One WAVE per node, 4 nodes per block.
// 16 lanes cover one 256 B Bh row (uint4 = 8 channels/lane); the 4 sub-groups
// of the wave cover 4 edges per load instruction. Main loop keeps 8 uint4
// loads in flight per lane (128 B outstanding). Sub-groups merged at the end
// with a 2-step shfl_xor max-reduce.
// ---------------------------------------------------------------------------
__global__ __launch_bounds__(256) void gather_kernel(
        const float* __restrict__ A,
        const uint4* __restrict__ Bh4,   // n_nodes x 16 uint4 (128 bf16)
        const int* __restrict__ offsets,
        const int* __restrict__ eidx,
        float* __restrict__ out,
        int n_nodes) {
    __shared__ int sidx[4][64];
    const int g = threadIdx.x >> 6;
    const int l = threadIdx.x & 63;
    const int n = blockIdx.x * 4 + g;
    if (n >= n_nodes) return;
    const int beg = offsets[n], end = offsets[n + 1];

    const int sub = l >> 4;   // which of 4 edges within a load group
    const int col = l & 15;   // 16 B column within the 256 B row

    float mlo[4][4], mhi[4][4];
    #pragma unroll
    for (int s = 0; s < 4; ++s)
        #pragma unroll
        for (int u = 0; u < 4; ++u) { mlo[s][u] = -INFINITY; mhi[s][u] = -INFINITY; }

    for (int base = beg; base < end; base += 64) {
        int p = base + l;
        if (p < end) sidx[g][l] = eidx[p];
        // single-wave lockstep: same-wave DS ordering makes the write visible
        int cnt = min(64, end - base);
        int q = 0;
        for (; q + 32 <= cnt; q += 32) {
            int e[8];
            #pragma unroll
            for (int s = 0; s < 8; ++s) e[s] = sidx[g][q + 4 * s + sub];
            uint4 w[8];
            #pragma unroll
            for (int s = 0; s < 8; ++s) w[s] = Bh4[(size_t)e[s] * 16 + col];
            #pragma unroll
            for (int s = 0; s < 8; ++s) {
                const int a = s & 3;
                mlo[a][0] = fmaxf(mlo[a][0], __uint_as_float(w[s].x << 16));
                mhi[a][0] = fmaxf(mhi[a][0], __uint_as_float(w[s].x & 0xFFFF0000u));
                mlo[a][1] = fmaxf(mlo[a][1], __uint_as_float(w[s].y << 16));
                mhi[a][1] = fmaxf(mhi[a][1], __uint_as_float(w[s].y & 0xFFFF0000u));
                mlo[a][2] = fmaxf(mlo[a][2], __uint_as_float(w[s].z << 16));
                mhi[a][2] = fmaxf(mhi[a][2], __uint_as_float(w[s].z & 0xFFFF0000u));
                mlo[a][3] = fmaxf(mlo[a][3], __uint_as_float(w[s].w << 16));
                mhi[a][3] = fmaxf(mhi[a][3], __uint_as_float(w[s].w & 0xFFFF0000u));
            }
        }
        for (; q < cnt; q += 4) {
            int r = q + sub;
            if (r < cnt) {
                int e = sidx[g][r];
                uint4 w = Bh4[(size_t)e * 16 + col];
                mlo[0][0] = fmaxf(mlo[0][0], __uint_as_float(w.x << 16));
                mhi[0][0] = fmaxf(mhi[0][0], __uint_as_float(w.x & 0xFFFF0000u));
                mlo[0][1] = fmaxf(mlo[0][1], __uint_as_float(w.y << 16));
                mhi[0][1] = fmaxf(mhi[0][1], __uint_as_float(w.y & 0xFFFF0000u));
                mlo[0][2] = fmaxf(mlo[0][2], __uint_as_float(w.z << 16));
                mhi[0][2] = fmaxf(mhi[0][2], __uint_as_float(w.z & 0xFFFF0000u));
                mlo[0][3] = fmaxf(mlo[0][3], __uint_as_float(w.w << 16));
                mhi[0][3] = fmaxf(mhi[0][3], __uint_as_float(w.w & 0xFFFF0000u));
            }
        }
    }

    // merge the 4 accumulator banks
    float lo[4], hi[4];
    #pragma unroll
    for (int u = 0; u < 4; ++u) {
        lo[u] = fmaxf(fmaxf(mlo[0][u], mlo[1][u]), fmaxf(mlo[2][u], mlo[3][u]));
        hi[u] = fmaxf(fmaxf(mhi[0][u], mhi[1][u]), fmaxf(mhi[2][u], mhi[3][u]));
    }
    // reduce across the 4 sub-groups (lanes sharing `col`)
    #pragma unroll
    for (int u = 0; u < 4; ++u) {
        lo[u] = fmaxf(lo[u], __shfl_xor(lo[u], 16, 64));
        hi[u] = fmaxf(hi[u], __shfl_xor(hi[u], 16, 64));
        lo[u] = fmaxf(lo[u], __shfl_xor(lo[u], 32, 64));
        hi[u] = fmaxf(hi[u], __shfl_xor(hi[u], 32, 64));
    }

    if (sub == 0) {
        float r8[8];
        if (end > beg) {
            const float4* Arow = (const float4*)(A + (size_t)n * N_CH + col * 8);
            float4 a0 = Arow[0], a1 = Arow[1];
            r8[0] = a0.x + lo[0]; r8[1] = a0.y + hi[0];
            r8[2] = a0.z + lo[1]; r8[3] = a0.w + hi[1];
            r8[4] = a1.x + lo[2]; r8[5] = a1.y + hi[2];
            r8[6] = a1.z + lo[3]; r8[7] = a1.w + hi[3];
        } else {
            #pragma unroll
            for (int i = 0; i < 8; ++i) r8[i] = 0.f;
        }
        float4* orow = (float4*)(out + (size_t)n * N_CH + col * 8);
        orow[0] = make_float4(r8[0], r8[1], r8[2], r8[3]);
        orow[1] = make_float4(r8[4], r8[5], r8[6], r8[7]);
    }
}

// ---------------------------------------------------------------------------
extern "C" void kernel_launch(void* const* d_in, const int* in_sizes, int n_in,
                              void* d_out, int out_size, void* d_ws, size_t ws_size,
                              hipStream_t stream) {
    const float* x = (const float*)d_in[0];
    const float* W = (const float*)d_in[1];
    const float* b = (const float*)d_in[2];
    const int*   ei = (const int*)d_in[3];

    const int n_nodes = in_sizes[0] / N_CH;   // 10000
    const int n_edges = in_sizes[3] / 2;      // 640000
    const int* src = ei;
    const int* dst = ei + n_edges;
    float* out = (float*)d_out;

    char* ws = (char*)d_ws;
    size_t off = 0;
    auto alloc = [&](size_t bytes) -> void* {
        void* p = ws + off;
        off += (bytes + 255) & ~(size_t)255;
        return p;
    };
    float* V1        = (float*)alloc((size_t)N_CH * N_CH * 4);
    float* V2        = (float*)alloc((size_t)N_CH * N_CH * 4);
    float* A         = (float*)alloc((size_t)n_nodes * N_CH * 4);
    unsigned short* Bh = (unsigned short*)alloc((size_t)n_nodes * N_CH * 2);
    int*   nodeCount = (int*)alloc((size_t)n_nodes * 4);
    int*   offsets   = (int*)alloc((size_t)(n_nodes + 1) * 4);
    int*   cursor    = (int*)alloc((size_t)n_nodes * 4);
    int*   eidx      = (int*)alloc((size_t)n_edges * 4);
    (void)ws_size; (void)n_in; (void)out_size;

    const int ne4 = (n_edges + 1023) / 1024;   // blocks at 4 edges/thread

    prep_kernel   <<<64, 256, 0, stream>>>(W, V1, V2, nodeCount, n_nodes);
    gemm_kernel   <<<(n_nodes + 31) / 32, 256, 0, stream>>>(x, V1, V2, b, A, Bh, n_nodes);
    hist_kernel   <<<ne4, 256, 0, stream>>>(dst, nodeCount, n_edges);
    scan_kernel   <<<1, 1024, 0, stream>>>(nodeCount, offsets, cursor, n_nodes);
    scatter_kernel<<<ne4, 256, 0, stream>>>(src, dst, cursor, eidx, n_edges);
    gather_kernel <<<(n_nodes + 3) / 4, 256, 0, stream>>>(A, (const uint4*)Bh, offsets, eidx, out, n_nodes);
}

// Round 4
// 136.564 us; speedup vs baseline: 1.9190x; 1.4673x over previous
//
#include <hip/hip_runtime.h>
#include <math.h>

#define N_CH 128
#define NB_MAX 512      // max bucket count (n_nodes <= 16384 -> nb <= 512)
#define ECHUNK 2048     // edges per hist/bin block
#define GCHUNK 2048     // records per gather CSR chunk

// ---------------------------------------------------------------------------
// K0: V1t[k*128+o] = W[o][k] - W[o][128+k], V2t[k*128+o] = W[o][128+k];
//     zero bucket histogram + cursors.
// ---------------------------------------------------------------------------
__global__ __launch_bounds__(256) void prep_kernel(const float* __restrict__ W,
                                                   float* __restrict__ V1,
                                                   float* __restrict__ V2,
                                                   int* __restrict__ binCount,
                                                   int* __restrict__ binCursor,
                                                   int nb) {
    int i = blockIdx.x * 256 + threadIdx.x;
    if (i < N_CH * N_CH) {
        int k = i >> 7, o = i & 127;
        float w1 = W[o * 256 + k];
        float w2 = W[o * 256 + 128 + k];
        V1[i] = w1 - w2;
        V2[i] = w2;
    }
    if (i < nb) { binCount[i] = 0; binCursor[i] = 0; }
}

// ---------------------------------------------------------------------------
// K1: fused GEMM + LDS-staged bucket histogram.
// ---------------------------------------------------------------------------
__global__ __launch_bounds__(256) void gemm_kernel(const float* __restrict__ x,
                                                   const float* __restrict__ V1,
                                                   const float* __restrict__ V2,
                                                   const float* __restrict__ bias,
                                                   const int* __restrict__ dst,
                                                   float* __restrict__ A,
                                                   unsigned short* __restrict__ Bh,
                                                   int* __restrict__ binCount,
                                                   int n_nodes, int n_edges, int nb) {
    __shared__ float xs[32][N_CH];      // 16 KB
    __shared__ int h[NB_MAX];           // 2 KB
    const int tid = threadIdx.x;
    const int bid = blockIdx.x;

    // --- LDS bucket histogram of this block's edge chunk ---
    const int ebase = bid * ECHUNK;
    const int ecnt = min(ECHUNK, n_edges - ebase);
    for (int i = tid; i < nb; i += 256) h[i] = 0;
    __syncthreads();
    if (ecnt > 0) {
        const int j = tid * 8;
        if (j + 8 <= ecnt) {
            int4 d0 = *(const int4*)(dst + ebase + j);
            int4 d1 = *(const int4*)(dst + ebase + j + 4);
            atomicAdd(&h[d0.x >> 5], 1); atomicAdd(&h[d0.y >> 5], 1);
            atomicAdd(&h[d0.z >> 5], 1); atomicAdd(&h[d0.w >> 5], 1);
            atomicAdd(&h[d1.x >> 5], 1); atomicAdd(&h[d1.y >> 5], 1);
            atomicAdd(&h[d1.z >> 5], 1); atomicAdd(&h[d1.w >> 5], 1);
        } else {
            for (int q = j; q < min(j + 8, ecnt); ++q)
                atomicAdd(&h[dst[ebase + q] >> 5], 1);
        }
    }
    __syncthreads();
    for (int i = tid; i < nb; i += 256)
        if (h[i]) atomicAdd(&binCount[i], h[i]);   // fire-and-forget

    // --- GEMM: 32 nodes per block (verified round-0 structure) ---
    const int n0 = bid * 32;
    if (n0 >= n_nodes) return;

    if (n0 + 32 <= n_nodes) {
        const float4* xg = (const float4*)(x + (size_t)n0 * N_CH);
        float4* xsv = (float4*)&xs[0][0];
        #pragma unroll
        for (int i = 0; i < 4; ++i) xsv[tid + i * 256] = xg[tid + i * 256];
    } else {
        for (int i = tid; i < 32 * N_CH; i += 256) {
            int n = n0 + (i >> 7);
            (&xs[0][0])[i] = (n < n_nodes) ? x[(size_t)n * N_CH + (i & 127)] : 0.f;
        }
    }
    __syncthreads();

    const int o  = tid & 127;
    const int nh = tid >> 7;            // 0 or 1
    const float bo = bias[o];
    float acc1[16], acc2[16];
    #pragma unroll
    for (int i = 0; i < 16; ++i) { acc1[i] = 0.f; acc2[i] = 0.f; }

    const float* xrow = &xs[nh * 16][0];
    for (int k4 = 0; k4 < N_CH; k4 += 4) {
        float w1[4], w2[4];
        #pragma unroll
        for (int j = 0; j < 4; ++j) {
            w1[j] = V1[(k4 + j) * N_CH + o];
            w2[j] = V2[(k4 + j) * N_CH + o];
        }
        #pragma unroll
        for (int i = 0; i < 16; ++i) {
            float4 xv = *(const float4*)&xrow[i * N_CH + k4];
            acc1[i] = fmaf(xv.x, w1[0], acc1[i]); acc2[i] = fmaf(xv.x, w2[0], acc2[i]);
            acc1[i] = fmaf(xv.y, w1[1], acc1[i]); acc2[i] = fmaf(xv.y, w2[1], acc2[i]);
            acc1[i] = fmaf(xv.z, w1[2], acc1[i]); acc2[i] = fmaf(xv.z, w2[2], acc2[i]);
            acc1[i] = fmaf(xv.w, w1[3], acc1[i]); acc2[i] = fmaf(xv.w, w2[3], acc2[i]);
        }
    }

    #pragma unroll
    for (int i = 0; i < 16; ++i) {
        int n = n0 + nh * 16 + i;
        if (n < n_nodes) {
            A[(size_t)n * N_CH + o] = acc1[i] + bo;
            // bf16 round-to-nearest-even
            unsigned int bits = __float_as_uint(acc2[i]);
            unsigned int r = (bits + 0x7FFFu + ((bits >> 16) & 1u)) >> 16;
            Bh[(size_t)n * N_CH + o] = (unsigned short)r;
        }
    }
}

// ---------------------------------------------------------------------------
// K2: lean bin scatter. Local padded scan (block 0 publishes binOffG), LDS
// atomic ranks, per-bucket global reservation, direct packed writes.
// ---------------------------------------------------------------------------
__global__ __launch_bounds__(256) void bin_kernel(const int* __restrict__ src,
                                                  const int* __restrict__ dst,
                                                  const int* __restrict__ binCount,
                                                  int* __restrict__ binCursor,
                                                  int* __restrict__ binOffG,
                                                  unsigned int* __restrict__ binned,
                                                  int n_edges, int nb) {
    __shared__ int sc[512];     // scan buffer, then per-bucket hist
    __shared__ int bOff[512];   // padded exclusive offsets, then bucket bases
    const int tid = threadIdx.x;
    const int base = blockIdx.x * ECHUNK;
    const int cnt = min(ECHUNK, n_edges - base);

    // --- padded exclusive scan of binCount (512 slots, 256 threads) ---
    int c0 = (tid < nb) ? binCount[tid] : 0;
    int c1 = (tid + 256 < nb) ? binCount[tid + 256] : 0;
    int p0 = (c0 + 3) & ~3, p1 = (c1 + 3) & ~3;
    sc[tid] = p0; sc[tid + 256] = p1;
    __syncthreads();
    #pragma unroll
    for (int off = 1; off < 512; off <<= 1) {
        int u0 = (tid >= off) ? sc[tid - off] : 0;
        int u1 = sc[tid + 256 - off];
        __syncthreads();
        sc[tid] += u0; sc[tid + 256] += u1;
        __syncthreads();
    }
    bOff[tid] = sc[tid] - p0;
    bOff[tid + 256] = sc[tid + 256] - p1;
    if (blockIdx.x == 0) {
        if (tid < nb) binOffG[tid] = bOff[tid];
        if (tid + 256 < nb) binOffG[tid + 256] = bOff[tid + 256];
    }
    sc[tid] = 0; sc[tid + 256] = 0;   // reuse as block-local bucket hist
    __syncthreads();

    // --- load 8 edges, rank via LDS atomics ---
    const int myb = tid * 8;
    const int mycnt = max(0, min(8, cnt - myb));
    unsigned int pk[8]; int bb[8], rr[8];
    if (mycnt == 8) {
        int4 s0 = *(const int4*)(src + base + myb);
        int4 s1 = *(const int4*)(src + base + myb + 4);
        int4 d0 = *(const int4*)(dst + base + myb);
        int4 d1 = *(const int4*)(dst + base + myb + 4);
        int sv[8] = {s0.x, s0.y, s0.z, s0.w, s1.x, s1.y, s1.z, s1.w};
        int dv[8] = {d0.x, d0.y, d0.z, d0.w, d1.x, d1.y, d1.z, d1.w};
        #pragma unroll
        for (int k = 0; k < 8; ++k) {
            int b = dv[k] >> 5;
            pk[k] = ((unsigned int)(dv[k] & 31) << 14) | (unsigned int)sv[k];
            bb[k] = b;
            rr[k] = atomicAdd(&sc[b], 1);
        }
    } else {
        for (int k = 0; k < mycnt; ++k) {
            int s = src[base + myb + k];
            int d = dst[base + myb + k];
            int b = d >> 5;
            pk[k] = ((unsigned int)(d & 31) << 14) | (unsigned int)s;
            bb[k] = b;
            rr[k] = atomicAdd(&sc[b], 1);
        }
    }
    __syncthreads();

    // --- reserve per-bucket global ranges ---
    for (int i = tid; i < nb; i += 256) {
        int c = sc[i];
        if (c) bOff[i] += atomicAdd(&binCursor[i], c);
    }
    __syncthreads();

    // --- write packed records ---
    for (int k = 0; k < mycnt; ++k)
        binned[bOff[bb[k]] + rr[k]] = pk[k];
}

// ---------------------------------------------------------------------------
// K3: fused CSR-build + gather-max. One block (512 thr = 8 waves) per bucket.
// Per-lane accumulators kept per-uint (channel pairs) as in the verified
// gather; sub-groups merged at the end with a 2-step shfl_xor reduce.
// ---------------------------------------------------------------------------
#define FOLD4(acc_lo, acc_hi, a, b, c, d)                                        \
    acc_lo = fmaxf(acc_lo, fmaxf(fmaxf(__uint_as_float((a) << 16),               \
                                       __uint_as_float((b) << 16)),              \
                                 fmaxf(__uint_as_float((c) << 16),               \
                                       __uint_as_float((d) << 16))));            \
    acc_hi = fmaxf(acc_hi, fmaxf(fmaxf(__uint_as_float((a) & 0xFFFF0000u),       \
                                       __uint_as_float((b) & 0xFFFF0000u)),      \
                                 fmaxf(__uint_as_float((c) & 0xFFFF0000u),       \
                                       __uint_as_float((d) & 0xFFFF0000u))));

__global__ __launch_bounds__(512) void gather_kernel(
        const float* __restrict__ A,
        const uint4* __restrict__ Bh4,   // n_nodes x 16 uint4 (128 bf16)
        const int* __restrict__ binOffG,
        const int* __restrict__ binCount,
        const unsigned int* __restrict__ binned,
        float* __restrict__ out,
        int n_nodes) {
    __shared__ int lidx[GCHUNK];        // 8 KB
    __shared__ int h32[32], e33[33];
    const int b = blockIdx.x;
    const int tid = threadIdx.x;
    const int wv  = tid >> 6;           // wave 0..7
    const int l   = tid & 63;
    const int sub = l >> 4;             // edge slot within load group
    const int col = l & 15;             // 16 B column within the 256 B row
    const int rbeg = binOffG[b];
    const int cnt  = binCount[b];

    float mlo[4][4], mhi[4][4]; int tcnt[4];
    #pragma unroll
    for (int i = 0; i < 4; ++i) {
        tcnt[i] = 0;
        #pragma unroll
        for (int u = 0; u < 4; ++u) { mlo[i][u] = -INFINITY; mhi[i][u] = -INFINITY; }
    }

    for (int cb = 0; cb < cnt; cb += GCHUNK) {
        const int ccnt = min(GCHUNK, cnt - cb);
        if (tid < 32) h32[tid] = 0;
        __syncthreads();

        // load + rank this chunk's records
        const int mb = tid * 4;
        const int mc = max(0, min(4, ccnt - mb));
        int myd[4], mys[4], myr[4];
        if (mc == 4) {
            int4 r4 = *(const int4*)((const int*)binned + rbeg + cb + mb);
            unsigned int wv4[4] = {(unsigned int)r4.x, (unsigned int)r4.y,
                                   (unsigned int)r4.z, (unsigned int)r4.w};
            #pragma unroll
            for (int k = 0; k < 4; ++k) {
                myd[k] = (int)(wv4[k] >> 14);
                mys[k] = (int)(wv4[k] & 16383u);
                myr[k] = atomicAdd(&h32[myd[k]], 1);
            }
        } else {
            for (int k = 0; k < mc; ++k) {
                unsigned int w = binned[rbeg + cb + mb + k];
                myd[k] = (int)(w >> 14);
                mys[k] = (int)(w & 16383u);
                myr[k] = atomicAdd(&h32[myd[k]], 1);
            }
        }
        __syncthreads();
        if (tid == 0) {
            int s = 0;
            #pragma unroll
            for (int k = 0; k < 32; ++k) { e33[k] = s; s += h32[k]; }
            e33[32] = s;
        }
        __syncthreads();
        for (int k = 0; k < mc; ++k)
            lidx[e33[myd[k]] + myr[k]] = mys[k];
        __syncthreads();

        // gather: 4 nodes per wave
        #pragma unroll
        for (int i = 0; i < 4; ++i) {
            const int nl = wv * 4 + i;
            const int c  = h32[nl];
            const int bg = e33[nl];
            tcnt[i] += c;
            int q = 0;
            for (; q + 16 <= c; q += 16) {
                int e0 = lidx[bg + q + sub];
                int e1 = lidx[bg + q + 4 + sub];
                int e2 = lidx[bg + q + 8 + sub];
                int e3 = lidx[bg + q + 12 + sub];
                uint4 w0 = Bh4[(size_t)e0 * 16 + col];
                uint4 w1 = Bh4[(size_t)e1 * 16 + col];
                uint4 w2 = Bh4[(size_t)e2 * 16 + col];
                uint4 w3 = Bh4[(size_t)e3 * 16 + col];
                FOLD4(mlo[i][0], mhi[i][0], w0.x, w1.x, w2.x, w3.x);
                FOLD4(mlo[i][1], mhi[i][1], w0.y, w1.y, w2.y, w3.y);
                FOLD4(mlo[i][2], mhi[i][2], w0.z, w1.z, w2.z, w3.z);
                FOLD4(mlo[i][3], mhi[i][3], w0.w, w1.w, w2.w, w3.w);
            }
            for (; q < c; q += 4) {
                int r = q + sub;
                if (r < c) {
                    uint4 w = Bh4[(size_t)lidx[bg + r] * 16 + col];
                    mlo[i][0] = fmaxf(mlo[i][0], __uint_as_float(w.x << 16));
                    mhi[i][0] = fmaxf(mhi[i][0], __uint_as_float(w.x & 0xFFFF0000u));
                    mlo[i][1] = fmaxf(mlo[i][1], __uint_as_float(w.y << 16));
                    mhi[i][1] = fmaxf(mhi[i][1], __uint_as_float(w.y & 0xFFFF0000u));
                    mlo[i][2] = fmaxf(mlo[i][2], __uint_as_float(w.z << 16));
                    mhi[i][2] = fmaxf(mhi[i][2], __uint_as_float(w.z & 0xFFFF0000u));
                    mlo[i][3] = fmaxf(mlo[i][3], __uint_as_float(w.w << 16));
                    mhi[i][3] = fmaxf(mhi[i][3], __uint_as_float(w.w & 0xFFFF0000u));
                }
            }
        }
        __syncthreads();
    }

    // epilogue: reduce sub-groups, add A, write (isolated nodes -> 0)
    #pragma unroll
    for (int i = 0; i < 4; ++i) {
        const int n = b * 32 + wv * 4 + i;
        if (n >= n_nodes) continue;
        float lo[4], hi[4];
        #pragma unroll
        for (int u = 0; u < 4; ++u) {
            lo[u] = mlo[i][u]; hi[u] = mhi[i][u];
            lo[u] = fmaxf(lo[u], __shfl_xor(lo[u], 16, 64));
            hi[u] = fmaxf(hi[u], __shfl_xor(hi[u], 16, 64));
            lo[u] = fmaxf(lo[u], __shfl_xor(lo[u], 32, 64));
            hi[u] = fmaxf(hi[u], __shfl_xor(hi[u], 32, 64));
        }
        if (sub == 0) {
            float r8[8];
            if (tcnt[i] > 0) {
                const float4* Arow = (const float4*)(A + (size_t)n * N_CH + col * 8);
                float4 a0 = Arow[0], a1 = Arow[1];
                r8[0] = a0.x + lo[0]; r8[1] = a0.y + hi[0];
                r8[2] = a0.z + lo[1]; r8[3] = a0.w + hi[1];
                r8[4] = a1.x + lo[2]; r8[5] = a1.y + hi[2];
                r8[6] = a1.z + lo[3]; r8[7] = a1.w + hi[3];
            } else {
                #pragma unroll
                for (int j = 0; j < 8; ++j) r8[j] = 0.f;
            }
            float4* orow = (float4*)(out + (size_t)n * N_CH + col * 8);
            orow[0] = make_float4(r8[0], r8[1], r8[2], r8[3]);
            orow[1] = make_float4(r8[4], r8[5], r8[6], r8[7]);
        }
    }
}

// ---------------------------------------------------------------------------
extern "C" void kernel_launch(void* const* d_in, const int* in_sizes, int n_in,
                              void* d_out, int out_size, void* d_ws, size_t ws_size,
                              hipStream_t stream) {
    const float* x = (const float*)d_in[0];
    const float* W = (const float*)d_in[1];
    const float* b = (const float*)d_in[2];
    const int*   ei = (const int*)d_in[3];

    const int n_nodes = in_sizes[0] / N_CH;   // 10000
    const int n_edges = in_sizes[3] / 2;      // 640000
    const int nb = (n_nodes + 31) >> 5;       // 313 buckets of 32 nodes
    const int* src = ei;
    const int* dst = ei + n_edges;
    float* out = (float*)d_out;

    char* ws = (char*)d_ws;
    size_t off = 0;
    auto alloc = [&](size_t bytes) -> void* {
        void* p = ws + off;
        off += (bytes + 255) & ~(size_t)255;
        return p;
    };
    float* V1        = (float*)alloc((size_t)N_CH * N_CH * 4);
    float* V2        = (float*)alloc((size_t)N_CH * N_CH * 4);
    float* A         = (float*)alloc((size_t)n_nodes * N_CH * 4);
    unsigned short* Bh = (unsigned short*)alloc((size_t)n_nodes * N_CH * 2);
    int*   binCount  = (int*)alloc((size_t)nb * 4);
    int*   binCursor = (int*)alloc((size_t)nb * 4);
    int*   binOffG   = (int*)alloc((size_t)nb * 4);
    unsigned int* binned = (unsigned int*)alloc(((size_t)n_edges + 4 * NB_MAX) * 4);
    (void)ws_size; (void)n_in; (void)out_size;

    const int nodeBlocks = (n_nodes + 31) / 32;
    const int edgeBlocks = (n_edges + ECHUNK - 1) / ECHUNK;
    const int ng = max(nodeBlocks, edgeBlocks);

    prep_kernel  <<<64, 256, 0, stream>>>(W, V1, V2, binCount, binCursor, nb);
    gemm_kernel  <<<ng, 256, 0, stream>>>(x, V1, V2, b, dst, A, Bh, binCount,
                                          n_nodes, n_edges, nb);
    bin_kernel   <<<edgeBlocks, 256, 0, stream>>>(src, dst, binCount, binCursor,
                                                  binOffG, binned, n_edges, nb);
    gather_kernel<<<nb, 512, 0, stream>>>(A, (const uint4*)Bh, binOffG, binCount,
                                          binned, out, n_nodes);
}

// Round 5
// 133.839 us; speedup vs baseline: 1.9581x; 1.0204x over previous
//
#include <hip/hip_runtime.h>
#include <math.h>

#define N_CH 128
#define NB_MAX 1024     // max bucket count (n_nodes <= 16384 -> nb <= 1024)
#define ECHUNK 2048     // edges per hist/bin block
#define GCHUNK 2048     // records per gather CSR chunk

// ---------------------------------------------------------------------------
// K0: weight prep in float4-friendly layout:
//   V1p[(k>>2)*512 + o*4 + (k&3)] = W[o][k] - W[o][128+k]
//   V2p[(k>>2)*512 + o*4 + (k&3)] = W[o][128+k]
// zero bucket histogram + cursors.
// ---------------------------------------------------------------------------
__global__ __launch_bounds__(256) void prep_kernel(const float* __restrict__ W,
                                                   float* __restrict__ V1,
                                                   float* __restrict__ V2,
                                                   int* __restrict__ binCount,
                                                   int* __restrict__ binCursor,
                                                   int nb) {
    int i = blockIdx.x * 256 + threadIdx.x;
    if (i < N_CH * N_CH) {
        int k = i >> 7, o = i & 127;
        float w1 = W[o * 256 + k];
        float w2 = W[o * 256 + 128 + k];
        int ip = (k >> 2) * 512 + o * 4 + (k & 3);
        V1[ip] = w1 - w2;
        V2[ip] = w2;
    }
    if (i < nb) { binCount[i] = 0; binCursor[i] = 0; }
}

// ---------------------------------------------------------------------------
// K1: fused GEMM + LDS-staged bucket histogram (bucket = dst >> 4).
// GEMM: A = x @ V1 + bias (fp32), Bh = bf16(x @ V2). 32 nodes/block.
// Weights read as float4 (16 B/lane coalesced).
// ---------------------------------------------------------------------------
__global__ __launch_bounds__(256) void gemm_kernel(const float* __restrict__ x,
                                                   const float* __restrict__ V1,
                                                   const float* __restrict__ V2,
                                                   const float* __restrict__ bias,
                                                   const int* __restrict__ dst,
                                                   float* __restrict__ A,
                                                   unsigned short* __restrict__ Bh,
                                                   int* __restrict__ binCount,
                                                   int n_nodes, int n_edges, int nb) {
    __shared__ float xs[32][N_CH];      // 16 KB
    __shared__ int h[NB_MAX];           // 4 KB
    const int tid = threadIdx.x;
    const int bid = blockIdx.x;

    // --- LDS bucket histogram of this block's edge chunk ---
    const int ebase = bid * ECHUNK;
    const int ecnt = min(ECHUNK, n_edges - ebase);
    for (int i = tid; i < nb; i += 256) h[i] = 0;
    __syncthreads();
    if (ecnt > 0) {
        const int j = tid * 8;
        if (j + 8 <= ecnt) {
            int4 d0 = *(const int4*)(dst + ebase + j);
            int4 d1 = *(const int4*)(dst + ebase + j + 4);
            atomicAdd(&h[d0.x >> 4], 1); atomicAdd(&h[d0.y >> 4], 1);
            atomicAdd(&h[d0.z >> 4], 1); atomicAdd(&h[d0.w >> 4], 1);
            atomicAdd(&h[d1.x >> 4], 1); atomicAdd(&h[d1.y >> 4], 1);
            atomicAdd(&h[d1.z >> 4], 1); atomicAdd(&h[d1.w >> 4], 1);
        } else {
            for (int q = j; q < min(j + 8, ecnt); ++q)
                atomicAdd(&h[dst[ebase + q] >> 4], 1);
        }
    }
    __syncthreads();
    for (int i = tid; i < nb; i += 256)
        if (h[i]) atomicAdd(&binCount[i], h[i]);   // fire-and-forget

    // --- GEMM: 32 nodes per block (verified structure) ---
    const int n0 = bid * 32;
    if (n0 >= n_nodes) return;

    if (n0 + 32 <= n_nodes) {
        const float4* xg = (const float4*)(x + (size_t)n0 * N_CH);
        float4* xsv = (float4*)&xs[0][0];
        #pragma unroll
        for (int i = 0; i < 4; ++i) xsv[tid + i * 256] = xg[tid + i * 256];
    } else {
        for (int i = tid; i < 32 * N_CH; i += 256) {
            int n = n0 + (i >> 7);
            (&xs[0][0])[i] = (n < n_nodes) ? x[(size_t)n * N_CH + (i & 127)] : 0.f;
        }
    }
    __syncthreads();

    const int o  = tid & 127;
    const int nh = tid >> 7;            // 0 or 1
    const float bo = bias[o];
    float acc1[16], acc2[16];
    #pragma unroll
    for (int i = 0; i < 16; ++i) { acc1[i] = 0.f; acc2[i] = 0.f; }

    const float* xrow = &xs[nh * 16][0];
    for (int k4 = 0; k4 < N_CH; k4 += 4) {
        float4 w1 = *(const float4*)(V1 + k4 * 128 + o * 4);
        float4 w2 = *(const float4*)(V2 + k4 * 128 + o * 4);
        #pragma unroll
        for (int i = 0; i < 16; ++i) {
            float4 xv = *(const float4*)&xrow[i * N_CH + k4];
            acc1[i] = fmaf(xv.x, w1.x, acc1[i]); acc2[i] = fmaf(xv.x, w2.x, acc2[i]);
            acc1[i] = fmaf(xv.y, w1.y, acc1[i]); acc2[i] = fmaf(xv.y, w2.y, acc2[i]);
            acc1[i] = fmaf(xv.z, w1.z, acc1[i]); acc2[i] = fmaf(xv.z, w2.z, acc2[i]);
            acc1[i] = fmaf(xv.w, w1.w, acc1[i]); acc2[i] = fmaf(xv.w, w2.w, acc2[i]);
        }
    }

    #pragma unroll
    for (int i = 0; i < 16; ++i) {
        int n = n0 + nh * 16 + i;
        if (n < n_nodes) {
            A[(size_t)n * N_CH + o] = acc1[i] + bo;
            // bf16 round-to-nearest-even
            unsigned int bits = __float_as_uint(acc2[i]);
            unsigned int r = (bits + 0x7FFFu + ((bits >> 16) & 1u)) >> 16;
            Bh[(size_t)n * N_CH + o] = (unsigned short)r;
        }
    }
}

// ---------------------------------------------------------------------------
// K2: lean bin scatter (bucket = dst >> 4). Hierarchical padded scan (4 slots
// per thread + 256-ladder; block 0 publishes binOffG), LDS atomic ranks,
// per-bucket global reservation, direct packed writes (dst&15)<<14 | src.
// ---------------------------------------------------------------------------
__global__ __launch_bounds__(256) void bin_kernel(const int* __restrict__ src,
                                                  const int* __restrict__ dst,
                                                  const int* __restrict__ binCount,
                                                  int* __restrict__ binCursor,
                                                  int* __restrict__ binOffG,
                                                  unsigned int* __restrict__ binned,
                                                  int n_edges, int nb) {
    __shared__ int sc[256];         // thread-sum scan buffer
    __shared__ int hist[NB_MAX];    // 4 KB: per-bucket hist
    __shared__ int bOff[NB_MAX];    // 4 KB: padded offsets -> bucket bases
    const int tid = threadIdx.x;
    const int base = blockIdx.x * ECHUNK;
    const int cnt = min(ECHUNK, n_edges - base);

    // --- hierarchical padded exclusive scan of binCount ---
    int p[4]; int s = 0;
    #pragma unroll
    for (int k = 0; k < 4; ++k) {
        int slot = tid * 4 + k;
        int c = (slot < nb) ? binCount[slot] : 0;
        p[k] = (c + 3) & ~3;        // 16 B-align each bucket region
        s += p[k];
    }
    sc[tid] = s;
    __syncthreads();
    #pragma unroll
    for (int off = 1; off < 256; off <<= 1) {
        int u = (tid >= off) ? sc[tid - off] : 0;
        __syncthreads();
        sc[tid] += u;
        __syncthreads();
    }
    int run = sc[tid] - s;
    #pragma unroll
    for (int k = 0; k < 4; ++k) {
        int slot = tid * 4 + k;
        bOff[slot] = run;
        run += p[k];
    }
    if (blockIdx.x == 0) {
        #pragma unroll
        for (int k = 0; k < 4; ++k) {
            int slot = tid * 4 + k;
            if (slot < nb) binOffG[slot] = bOff[slot];
        }
    }
    for (int i = tid; i < NB_MAX; i += 256) hist[i] = 0;
    __syncthreads();

    // --- load 8 edges, rank via LDS atomics ---
    const int myb = tid * 8;
    const int mycnt = max(0, min(8, cnt - myb));
    unsigned int pk[8]; int bb[8], rr[8];
    if (mycnt == 8) {
        int4 s0 = *(const int4*)(src + base + myb);
        int4 s1 = *(const int4*)(src + base + myb + 4);
        int4 d0 = *(const int4*)(dst + base + myb);
        int4 d1 = *(const int4*)(dst + base + myb + 4);
        int sv[8] = {s0.x, s0.y, s0.z, s0.w, s1.x, s1.y, s1.z, s1.w};
        int dv[8] = {d0.x, d0.y, d0.z, d0.w, d1.x, d1.y, d1.z, d1.w};
        #pragma unroll
        for (int k = 0; k < 8; ++k) {
            int b = dv[k] >> 4;
            pk[k] = ((unsigned int)(dv[k] & 15) << 14) | (unsigned int)sv[k];
            bb[k] = b;
            rr[k] = atomicAdd(&hist[b], 1);
        }
    } else {
        for (int k = 0; k < mycnt; ++k) {
            int sv = src[base + myb + k];
            int dv = dst[base + myb + k];
            int b = dv >> 4;
            pk[k] = ((unsigned int)(dv & 15) << 14) | (unsigned int)sv;
            bb[k] = b;
            rr[k] = atomicAdd(&hist[b], 1);
        }
    }
    __syncthreads();

    // --- reserve per-bucket global ranges ---
    for (int i = tid; i < nb; i += 256) {
        int c = hist[i];
        if (c) bOff[i] += atomicAdd(&binCursor[i], c);
    }
    __syncthreads();

    // --- write packed records ---
    for (int k = 0; k < mycnt; ++k)
        binned[bOff[bb[k]] + rr[k]] = pk[k];
}

// ---------------------------------------------------------------------------
// K3: fused CSR-build + gather-max. One block (256 thr = 4 waves) per 16-node
// bucket. Per chunk: build the 16-node CSR in LDS, then each wave gathers 4
// nodes: 16 lanes cover one 256 B Bh row (uint4 = 8 channels/lane); 4
// sub-groups -> 4 edges per wave-load, 4 loads in flight. Per-uint
// accumulators; sub-groups merged at the end with a 2-step shfl_xor reduce.
// ---------------------------------------------------------------------------
#define FOLD4(acc_lo, acc_hi, a, b, c, d)                                        \
    acc_lo = fmaxf(acc_lo, fmaxf(fmaxf(__uint_as_float((a) << 16),               \
                                       __uint_as_float((b) << 16)),              \
                                 fmaxf(__uint_as_float((c) << 16),               \
                                       __uint_as_float((d) << 16))));            \
    acc_hi = fmaxf(acc_hi, fmaxf(fmaxf(__uint_as_float((a) & 0xFFFF0000u),       \
                                       __uint_as_float((b) & 0xFFFF0000u)),      \
                                 fmaxf(__uint_as_float((c) & 0xFFFF0000u),       \
                                       __uint_as_float((d) & 0xFFFF0000u))));

__global__ __launch_bounds__(256) void gather_kernel(
        const float* __restrict__ A,
        const uint4* __restrict__ Bh4,   // n_nodes x 16 uint4 (128 bf16)
        const int* __restrict__ binOffG,
        const int* __restrict__ binCount,
        const unsigned int* __restrict__ binned,
        float* __restrict__ out,
        int n_nodes) {
    __shared__ int lidx[GCHUNK];        // 8 KB
    __shared__ int h16[16], e17[17];
    const int b = blockIdx.x;
    const int tid = threadIdx.x;
    const int wv  = tid >> 6;           // wave 0..3
    const int l   = tid & 63;
    const int sub = l >> 4;             // edge slot within load group
    const int col = l & 15;             // 16 B column within the 256 B row
    const int rbeg = binOffG[b];
    const int cnt  = binCount[b];

    float mlo[4][4], mhi[4][4]; int tcnt[4];
    #pragma unroll
    for (int i = 0; i < 4; ++i) {
        tcnt[i] = 0;
        #pragma unroll
        for (int u = 0; u < 4; ++u) { mlo[i][u] = -INFINITY; mhi[i][u] = -INFINITY; }
    }

    for (int cb = 0; cb < cnt; cb += GCHUNK) {
        const int ccnt = min(GCHUNK, cnt - cb);
        if (tid < 16) h16[tid] = 0;
        __syncthreads();

        // load + rank this chunk's records (8 per thread)
        const int mb = tid * 8;
        const int mc = max(0, min(8, ccnt - mb));
        int myd[8], mys[8], myr[8];
        if (mc == 8) {
            int4 r0 = *(const int4*)((const int*)binned + rbeg + cb + mb);
            int4 r1 = *(const int4*)((const int*)binned + rbeg + cb + mb + 4);
            unsigned int wv8[8] = {(unsigned int)r0.x, (unsigned int)r0.y,
                                   (unsigned int)r0.z, (unsigned int)r0.w,
                                   (unsigned int)r1.x, (unsigned int)r1.y,
                                   (unsigned int)r1.z, (unsigned int)r1.w};
            #pragma unroll
            for (int k = 0; k < 8; ++k) {
                myd[k] = (int)(wv8[k] >> 14);
                mys[k] = (int)(wv8[k] & 16383u);
                myr[k] = atomicAdd(&h16[myd[k]], 1);
            }
        } else {
            for (int k = 0; k < mc; ++k) {
                unsigned int w = binned[rbeg + cb + mb + k];
                myd[k] = (int)(w >> 14);
                mys[k] = (int)(w & 16383u);
                myr[k] = atomicAdd(&h16[myd[k]], 1);
            }
        }
        __syncthreads();
        if (tid == 0) {
            int s = 0;
            #pragma unroll
            for (int k = 0; k < 16; ++k) { e17[k] = s; s += h16[k]; }
            e17[16] = s;
        }
        __syncthreads();
        for (int k = 0; k < mc; ++k)
            lidx[e17[myd[k]] + myr[k]] = mys[k];
        __syncthreads();

        // gather: 4 nodes per wave
        #pragma unroll
        for (int i = 0; i < 4; ++i) {
            const int nl = wv * 4 + i;
            const int c  = h16[nl];
            const int bg = e17[nl];
            tcnt[i] += c;
            int q = 0;
            for (; q + 16 <= c; q += 16) {
                int e0 = lidx[bg + q + sub];
                int e1 = lidx[bg + q + 4 + sub];
                int e2 = lidx[bg + q + 8 + sub];
                int e3 = lidx[bg + q + 12 + sub];
                uint4 w0 = Bh4[(size_t)e0 * 16 + col];
                uint4 w1 = Bh4[(size_t)e1 * 16 + col];
                uint4 w2 = Bh4[(size_t)e2 * 16 + col];
                uint4 w3 = Bh4[(size_t)e3 * 16 + col];
                FOLD4(mlo[i][0], mhi[i][0], w0.x, w1.x, w2.x, w3.x);
                FOLD4(mlo[i][1], mhi[i][1], w0.y, w1.y, w2.y, w3.y);
                FOLD4(mlo[i][2], mhi[i][2], w0.z, w1.z, w2.z, w3.z);
                FOLD4(mlo[i][3], mhi[i][3], w0.w, w1.w, w2.w, w3.w);
            }
            for (; q < c; q += 4) {
                int r = q + sub;
                if (r < c) {
                    uint4 w = Bh4[(size_t)lidx[bg + r] * 16 + col];
                    mlo[i][0] = fmaxf(mlo[i][0], __uint_as_float(w.x << 16));
                    mhi[i][0] = fmaxf(mhi[i][0], __uint_as_float(w.x & 0xFFFF0000u));
                    mlo[i][1] = fmaxf(mlo[i][1], __uint_as_float(w.y << 16));
                    mhi[i][1] = fmaxf(mhi[i][1], __uint_as_float(w.y & 0xFFFF0000u));
                    mlo[i][2] = fmaxf(mlo[i][2], __uint_as_float(w.z << 16));
                    mhi[i][2] = fmaxf(mhi[i][2], __uint_as_float(w.z & 0xFFFF0000u));
                    mlo[i][3] = fmaxf(mlo[i][3], __uint_as_float(w.w << 16));
                    mhi[i][3] = fmaxf(mhi[i][3], __uint_as_float(w.w & 0xFFFF0000u));
                }
            }
        }
        __syncthreads();
    }

    // epilogue: reduce sub-groups, add A, write (isolated nodes -> 0)
    #pragma unroll
    for (int i = 0; i < 4; ++i) {
        const int n = b * 16 + wv * 4 + i;
        if (n >= n_nodes) continue;
        float lo[4], hi[4];
        #pragma unroll
        for (int u = 0; u < 4; ++u) {
            lo[u] = mlo[i][u]; hi[u] = mhi[i][u];
            lo[u] = fmaxf(lo[u], __shfl_xor(lo[u], 16, 64));
            hi[u] = fmaxf(hi[u], __shfl_xor(hi[u], 16, 64));
            lo[u] = fmaxf(lo[u], __shfl_xor(lo[u], 32, 64));
            hi[u] = fmaxf(hi[u], __shfl_xor(hi[u], 32, 64));
        }
        if (sub == 0) {
            float r8[8];
            if (tcnt[i] > 0) {
                const float4* Arow = (const float4*)(A + (size_t)n * N_CH + col * 8);
                float4 a0 = Arow[0], a1 = Arow[1];
                r8[0] = a0.x + lo[0]; r8[1] = a0.y + hi[0];
                r8[2] = a0.z + lo[1]; r8[3] = a0.w + hi[1];
                r8[4] = a1.x + lo[2]; r8[5] = a1.y + hi[2];
                r8[6] = a1.z + lo[3]; r8[7] = a1.w + hi[3];
            } else {
                #pragma unroll
                for (int j = 0; j < 8; ++j) r8[j] = 0.f;
            }
            float4* orow = (float4*)(out + (size_t)n * N_CH + col * 8);
            orow[0] = make_float4(r8[0], r8[1], r8[2], r8[3]);
            orow[1] = make_float4(r8[4], r8[5], r8[6], r8[7]);
        }
    }
}

// ---------------------------------------------------------------------------
extern "C" void kernel_launch(void* const* d_in, const int* in_sizes, int n_in,
                              void* d_out, int out_size, void* d_ws, size_t ws_size,
                              hipStream_t stream) {
    const float* x = (const float*)d_in[0];
    const float* W = (const float*)d_in[1];
    const float* b = (const float*)d_in[2];
    const int*   ei = (const int*)d_in[3];

    const int n_nodes = in_sizes[0] / N_CH;   // 10000
    const int n_edges = in_sizes[3] / 2;      // 640000
    const int nb = (n_nodes + 15) >> 4;       // 625 buckets of 16 nodes
    const int* src = ei;
    const int* dst = ei + n_edges;
    float* out = (float*)d_out;

    char* ws = (char*)d_ws;
    size_t off = 0;
    auto alloc = [&](size_t bytes) -> void* {
        void* p = ws + off;
        off += (bytes + 255) & ~(size_t)255;
        return p;
    };
    float* V1        = (float*)alloc((size_t)N_CH * N_CH * 4);
    float* V2        = (float*)alloc((size_t)N_CH * N_CH * 4);
    float* A         = (float*)alloc((size_t)n_nodes * N_CH * 4);
    unsigned short* Bh = (unsigned short*)alloc((size_t)n_nodes * N_CH * 2);
    int*   binCount  = (int*)alloc((size_t)nb * 4);
    int*   binCursor = (int*)alloc((size_t)nb * 4);
    int*   binOffG   = (int*)alloc((size_t)nb * 4);
    unsigned int* binned = (unsigned int*)alloc(((size_t)n_edges + 4 * NB_MAX) * 4);
    (void)ws_size; (void)n_in; (void)out_size;

    const int nodeBlocks = (n_nodes + 31) / 32;
    const int edgeBlocks = (n_edges + ECHUNK - 1) / ECHUNK;
    const int ng = max(nodeBlocks, edgeBlocks);

    prep_kernel  <<<64, 256, 0, stream>>>(W, V1, V2, binCount, binCursor, nb);
    gemm_kernel  <<<ng, 256, 0, stream>>>(x, V1, V2, b, dst, A, Bh, binCount,
                                          n_nodes, n_edges, nb);
    bin_kernel   <<<edgeBlocks, 256, 0, stream>>>(src, dst, binCount, binCursor,
                                                  binOffG, binned, n_edges, nb);
    gather_kernel<<<nb, 256, 0, stream>>>(A, (const uint4*)Bh, binOffG, binCount,
                                          binned, out, n_nodes);
}